// Round 4
// baseline (357.970 us; speedup 1.0000x reference)
//
#include <hip/hip_runtime.h>

// NCC loss: 9x9 box-filtered local cross-correlation, -mean(cc).
// Inputs: y_pred, y_true (32,4,512,512) fp32. Output: scalar fp32.
//
// R4: R3 structure (barrier-free, LDS-free, wave-autonomous, shfl halo,
// software-pipelined loads) with the off-by-one FIXED: advancing the
// window [y-4,y+4] -> [y-3,y+5] subtracts row y-PAD (= y-4), not y-3.

#define PAD 4
#define EPS 1e-5f

constexpr int B = 32, C = 4, H = 512, W = 512;
constexpr int ROWS = 16;               // rows per wave-task
constexpr int NCHUNK = H / ROWS;       // 32
constexpr int NTASK = B * C * NCHUNK;  // 4096 waves
constexpr int TPB = 256;
constexpr int WPB = TPB / 64;          // 4 independent waves per block
constexpr int NBLK = NTASK / WPB;      // 1024
constexpr float INV_N = 1.0f / 81.0f;

__device__ __forceinline__ void loadrow(const float* __restrict__ p, int r,
                                        int x0, float4& a, float4& b) {
    const float* q = p + (size_t)r * W + x0;
    a = *(const float4*)q;
    b = *(const float4*)(q + 4);
}

__device__ __forceinline__ void unpack8(const float4& a, const float4& b,
                                        float f[8]) {
    f[0] = a.x; f[1] = a.y; f[2] = a.z; f[3] = a.w;
    f[4] = b.x; f[5] = b.y; f[6] = b.z; f[7] = b.w;
}

// 9-wide horizontal sliding sum over this lane's 8 columns, halo via shfl.
__device__ __forceinline__ void hsum(const float sc[8], int lane, float h[8]) {
    float L[4], R[4];
#pragma unroll
    for (int k = 0; k < 4; ++k) {
        L[k] = __shfl_up(sc[4 + k], 1, 64);
        R[k] = __shfl_down(sc[k], 1, 64);
    }
#pragma unroll
    for (int k = 0; k < 4; ++k) {
        L[k] = (lane == 0) ? 0.0f : L[k];    // image left edge: SAME zero-pad
        R[k] = (lane == 63) ? 0.0f : R[k];   // image right edge
    }
    // window w[0..15] = L0..3, own0..7, R0..3 ; out col j uses w[j..j+8]
    float w[16] = {L[0], L[1], L[2], L[3],
                   sc[0], sc[1], sc[2], sc[3], sc[4], sc[5], sc[6], sc[7],
                   R[0], R[1], R[2], R[3]};
    float t = w[0] + w[1] + w[2] + w[3] + w[4] + w[5] + w[6] + w[7] + w[8];
    h[0] = t;
#pragma unroll
    for (int j = 1; j < 8; ++j) {
        t += w[j + 8] - w[j - 1];
        h[j] = t;
    }
}

__global__ __launch_bounds__(TPB, 4) void ncc_partial(
        const float* __restrict__ y_pred, const float* __restrict__ y_true,
        float* __restrict__ partial) {
    const int wid = threadIdx.x >> 6;
    const int lane = threadIdx.x & 63;
    // XCD-aware swizzle: consecutive tasks (vertical neighbors) -> same XCD.
    const int g = (blockIdx.x & 7) * (NBLK / 8) + (blockIdx.x >> 3);
    const int task = g * WPB + wid;                 // bijection over [0,4096)
    const int plane = task >> 5;                    // / NCHUNK
    const int v = task & (NCHUNK - 1);
    const size_t base = (size_t)plane * H * W;
    const float* I = y_true + base;  // reference: I = y_true
    const float* J = y_pred + base;  // reference: J = y_pred
    const int x0 = lane * 8;
    const int y0 = v * ROWS;

    // Running vertical sums over rows [y-4, y+4]: 5 moments x 8 cols.
    float s[5][8];
#pragma unroll
    for (int c = 0; c < 5; ++c)
#pragma unroll
        for (int k = 0; k < 8; ++k) s[c][k] = 0.0f;

    // Prime rows [y0-4, y0+4] ∩ [0,H)   (y0+4 <= 500 < H always)
    for (int r = y0 - PAD; r <= y0 + PAD; ++r) {
        if (r < 0) continue;
        float4 i0, i1, j0, j1;
        loadrow(I, r, x0, i0, i1);
        loadrow(J, r, x0, j0, j1);
        float fi[8], fj[8];
        unpack8(i0, i1, fi);
        unpack8(j0, j1, fj);
#pragma unroll
        for (int k = 0; k < 8; ++k) {
            const float a = fi[k], b = fj[k];
            s[0][k] += a; s[1][k] += b;
            s[2][k] += a * a; s[3][k] += b * b; s[4][k] += a * b;
        }
    }

    float acc = 0.0f;

    for (int yo = 0; yo < ROWS; ++yo) {
        const int y = y0 + yo;

        // --- 1. issue next add-row loads (row y+5); consumed at step 3 ---
        const int ra = y + PAD + 1;
        const bool va = (yo < ROWS - 1) && (ra < H);
        float4 ai0, ai1, aj0, aj1;
        if (va) { loadrow(I, ra, x0, ai0, ai1); loadrow(J, ra, x0, aj0, aj1); }

        // --- 2. horizontal sums + cc (independent of the loads above) ---
        float mI[8], mJ[8];
        hsum(s[0], lane, mI);
        hsum(s[1], lane, mJ);

        // issue next sub-row loads (row y-4, L3-resident) mid-compute
        const int rs = y - PAD;   // FIXED: window advance drops row y-4
        const bool vsub = (yo < ROWS - 1) && (rs >= 0);
        float4 si0, si1, sj0, sj1;
        if (vsub) { loadrow(I, rs, x0, si0, si1); loadrow(J, rs, x0, sj0, sj1); }

        float vI[8], vJ[8], cv[8];
        hsum(s[2], lane, vI);
        hsum(s[3], lane, vJ);
        hsum(s[4], lane, cv);

#pragma unroll
        for (int k = 0; k < 8; ++k) {
            const float mi = mI[k] * INV_N;
            const float mj = mJ[k] * INV_N;
            const float vi = vI[k] * INV_N - mi * mi;
            const float vj = vJ[k] * INV_N - mj * mj;
            const float c  = cv[k] * INV_N - mi * mj;
            const float den = fmaxf(vi, 0.0f) * fmaxf(vj, 0.0f) + EPS;
            acc += c * c * __builtin_amdgcn_rcpf(den);
        }

        // --- 3. fold prefetched rows into the running sums ---
        if (va) {
            float fi[8], fj[8];
            unpack8(ai0, ai1, fi);
            unpack8(aj0, aj1, fj);
#pragma unroll
            for (int k = 0; k < 8; ++k) {
                const float a = fi[k], b = fj[k];
                s[0][k] += a; s[1][k] += b;
                s[2][k] += a * a; s[3][k] += b * b; s[4][k] += a * b;
            }
        }
        if (vsub) {
            float fi[8], fj[8];
            unpack8(si0, si1, fi);
            unpack8(sj0, sj1, fj);
#pragma unroll
            for (int k = 0; k < 8; ++k) {
                const float a = fi[k], b = fj[k];
                s[0][k] -= a; s[1][k] -= b;
                s[2][k] -= a * a; s[3][k] -= b * b; s[4][k] -= a * b;
            }
        }
    }

    // Per-wave reduction; one partial per task (deterministic slot).
#pragma unroll
    for (int off = 32; off > 0; off >>= 1)
        acc += __shfl_down(acc, off, 64);
    if (lane == 0) partial[task] = acc;
}

__global__ __launch_bounds__(256) void ncc_final(
        const float* __restrict__ partial, float* __restrict__ out) {
    const int t = threadIdx.x;
    float sum = 0.0f;
    for (int i = t; i < NTASK; i += 256) sum += partial[i];
    __shared__ float ws[4];
#pragma unroll
    for (int off = 32; off > 0; off >>= 1)
        sum += __shfl_down(sum, off, 64);
    if ((t & 63) == 0) ws[t >> 6] = sum;
    __syncthreads();
    if (t == 0) {
        const float tot = ws[0] + ws[1] + ws[2] + ws[3];
        out[0] = -tot / (float)((long long)B * C * H * W);
    }
}

extern "C" void kernel_launch(void* const* d_in, const int* in_sizes, int n_in,
                              void* d_out, int out_size, void* d_ws, size_t ws_size,
                              hipStream_t stream) {
    const float* y_pred = (const float*)d_in[0];
    const float* y_true = (const float*)d_in[1];
    float* out = (float*)d_out;
    float* partial = (float*)d_ws;  // NTASK floats = 16 KB

    ncc_partial<<<NBLK, TPB, 0, stream>>>(y_pred, y_true, partial);
    ncc_final<<<1, 256, 0, stream>>>(partial, out);
}

// Round 5
// 113.950 us; speedup vs baseline: 3.1415x; 3.1415x over previous
//
#include <hip/hip_runtime.h>

// NCC loss: 9x9 box-filtered local cross-correlation, -mean(cc).
// Inputs: y_pred, y_true (32,4,512,512) fp32. Output: scalar fp32.
//
// R5: R1 structure (TPB=128, CPT=4, LDS horizontal pass, VGPR=52, no
// spills) with ROWS 32->16: grid 2048->4096 blocks lifts the occupancy
// cap from 50% to ~94% (15 blocks/CU @ 10.75KB LDS). Extra halo reads
// are L3 hits (inputs 238MB < 256MB L3). + XCD swizzle so vertically
// adjacent chunks share L2, + rcpf for the per-pixel divide.

#define PAD 4
#define EPS 1e-5f

constexpr int B = 32, C = 4, H = 512, W = 512;
constexpr int ROWS = 16;             // output rows per block (R1: 32)
constexpr int TPB = 128;             // threads per block (2 waves)
constexpr int CPT = 4;               // columns per thread (128*4 = 512 = W)
constexpr int SLOTS = 528;           // 4 halo + 512 + 4 halo, 16B-padded
constexpr int NCHUNK = H / ROWS;     // 32
constexpr int NBLK = B * C * NCHUNK; // 4096
constexpr float INV_N = 1.0f / 81.0f;

template <bool ADD>
__device__ __forceinline__ void accrow(const float* __restrict__ I,
                                       const float* __restrict__ J,
                                       int r, int x0,
                                       float sI[CPT], float sJ[CPT],
                                       float sI2[CPT], float sJ2[CPT],
                                       float sIJ[CPT]) {
    const float4 vi = *(const float4*)(I + (size_t)r * W + x0);
    const float4 vj = *(const float4*)(J + (size_t)r * W + x0);
    float fi[CPT] = {vi.x, vi.y, vi.z, vi.w};
    float fj[CPT] = {vj.x, vj.y, vj.z, vj.w};
#pragma unroll
    for (int k = 0; k < CPT; ++k) {
        float a = fi[k], b = fj[k];
        if (ADD) {
            sI[k] += a; sJ[k] += b;
            sI2[k] += a * a; sJ2[k] += b * b; sIJ[k] += a * b;
        } else {
            sI[k] -= a; sJ[k] -= b;
            sI2[k] -= a * a; sJ2[k] -= b * b; sIJ[k] -= a * b;
        }
    }
}

__global__ __launch_bounds__(TPB) void ncc_partial(
        const float* __restrict__ y_pred, const float* __restrict__ y_true,
        float* __restrict__ partial) {
    __shared__ float vs[5][SLOTS];
    __shared__ float wsum[TPB / 64];

    // XCD swizzle: blocks land on XCD (blockIdx%8); give each XCD a
    // contiguous task range so vertically-adjacent chunks (which share
    // 8 halo rows = 32KB) hit the same XCD's L2. Bijective: 4096 % 8 == 0.
    const int bid = (blockIdx.x & 7) * (NBLK / 8) + (blockIdx.x >> 3);
    const int chunk = bid % NCHUNK;
    const int plane = bid / NCHUNK;
    const size_t base = (size_t)plane * H * W;
    const float* I = y_true + base;  // reference: I = y_true
    const float* J = y_pred + base;  // reference: J = y_pred

    const int t = threadIdx.x;
    const int x0 = t * CPT;  // this thread's 4 output columns

    // Zero the halo slots once (SAME zero-padding); never rewritten.
    if (t < 2 * PAD) {
        int sl = (t < PAD) ? t : (512 + t);  // slots 0..3 and 516..519
#pragma unroll
        for (int ch = 0; ch < 5; ++ch) vs[ch][sl] = 0.0f;
    }

    const int y0 = chunk * ROWS;

    // Running vertical sums over rows [y-4, y+4] for 5 moment channels.
    float sI[CPT] = {0.f, 0.f, 0.f, 0.f}, sJ[CPT] = {0.f, 0.f, 0.f, 0.f};
    float sI2[CPT] = {0.f, 0.f, 0.f, 0.f}, sJ2[CPT] = {0.f, 0.f, 0.f, 0.f};
    float sIJ[CPT] = {0.f, 0.f, 0.f, 0.f};

    // Prime with rows [y0-4, y0+3] ∩ [0,H)
    for (int r = y0 - PAD; r < y0 + PAD; ++r) {
        if (r >= 0 && r < H)
            accrow<true>(I, J, r, x0, sI, sJ, sI2, sJ2, sIJ);
    }

    float acc = 0.0f;

    for (int yo = 0; yo < ROWS; ++yo) {
        const int y = y0 + yo;
        const int rin = y + PAD;
        if (rin < H) accrow<true>(I, J, rin, x0, sI, sJ, sI2, sJ2, sIJ);
        // vsums now cover rows [y-4, y+4] (zero outside image)

        __syncthreads();  // previous iteration's LDS reads complete
        *(float4*)&vs[0][x0 + PAD] = make_float4(sI[0], sI[1], sI[2], sI[3]);
        *(float4*)&vs[1][x0 + PAD] = make_float4(sJ[0], sJ[1], sJ[2], sJ[3]);
        *(float4*)&vs[2][x0 + PAD] = make_float4(sI2[0], sI2[1], sI2[2], sI2[3]);
        *(float4*)&vs[3][x0 + PAD] = make_float4(sJ2[0], sJ2[1], sJ2[2], sJ2[3]);
        *(float4*)&vs[4][x0 + PAD] = make_float4(sIJ[0], sIJ[1], sIJ[2], sIJ[3]);
        __syncthreads();

        // Horizontal 9-sum: window for output x0+k is slots [x0+k, x0+k+8].
        float h[5][CPT];
#pragma unroll
        for (int ch = 0; ch < 5; ++ch) {
            const float* row = vs[ch];
            const float4 a = *(const float4*)(row + x0);
            const float4 b = *(const float4*)(row + x0 + 4);
            const float4 c = *(const float4*)(row + x0 + 8);
            float s = a.x + a.y + a.z + a.w + b.x + b.y + b.z + b.w + c.x;
            h[ch][0] = s;
            s += c.y - a.x; h[ch][1] = s;
            s += c.z - a.y; h[ch][2] = s;
            s += c.w - a.z; h[ch][3] = s;
        }

#pragma unroll
        for (int k = 0; k < CPT; ++k) {
            const float mI = h[0][k] * INV_N;
            const float mJ = h[1][k] * INV_N;
            const float vI = h[2][k] * INV_N - mI * mI;
            const float vJ = h[3][k] * INV_N - mJ * mJ;
            const float cv = h[4][k] * INV_N - mI * mJ;
            const float den = fmaxf(vI, 0.0f) * fmaxf(vJ, 0.0f) + EPS;
            acc += cv * cv * __builtin_amdgcn_rcpf(den);
        }

        const int rout = y - PAD;
        if (rout >= 0) accrow<false>(I, J, rout, x0, sI, sJ, sI2, sJ2, sIJ);
    }

    // Block reduction (deterministic): wave shuffle + LDS
#pragma unroll
    for (int off = 32; off > 0; off >>= 1)
        acc += __shfl_down(acc, off, 64);
    __syncthreads();  // all vs reads done before wsum reuse window
    if ((t & 63) == 0) wsum[t >> 6] = acc;
    __syncthreads();
    if (t == 0) partial[bid] = wsum[0] + wsum[1];
}

__global__ __launch_bounds__(256) void ncc_final(
        const float* __restrict__ partial, float* __restrict__ out) {
    const int t = threadIdx.x;
    float s = 0.0f;
    for (int i = t; i < NBLK; i += 256) s += partial[i];
    __shared__ float ws[4];
#pragma unroll
    for (int off = 32; off > 0; off >>= 1)
        s += __shfl_down(s, off, 64);
    if ((t & 63) == 0) ws[t >> 6] = s;
    __syncthreads();
    if (t == 0) {
        const float tot = ws[0] + ws[1] + ws[2] + ws[3];
        out[0] = -tot / (float)((long long)B * C * H * W);
    }
}

extern "C" void kernel_launch(void* const* d_in, const int* in_sizes, int n_in,
                              void* d_out, int out_size, void* d_ws, size_t ws_size,
                              hipStream_t stream) {
    const float* y_pred = (const float*)d_in[0];
    const float* y_true = (const float*)d_in[1];
    float* out = (float*)d_out;
    float* partial = (float*)d_ws;  // NBLK floats = 16 KB

    ncc_partial<<<NBLK, TPB, 0, stream>>>(y_pred, y_true, partial);
    ncc_final<<<1, 256, 0, stream>>>(partial, out);
}

// Round 6
// 105.712 us; speedup vs baseline: 3.3863x; 1.0779x over previous
//
#include <hip/hip_runtime.h>

// NCC loss: 9x9 box-filtered local cross-correlation, -mean(cc).
// Inputs: y_pred, y_true (32,4,512,512) fp32. Output: scalar fp32.
//
// R6: R4 structure (barrier-free, LDS-free, wave-autonomous, shfl halo,
// loads prefetched a full iteration ahead of use) with the spill fixed:
// NO min-occupancy launch bound (R4's (256,4) pinned VGPR=64 vs ~130
// appetite -> 1.4GB scratch traffic), and cc computed in two 4-column
// halves to shrink live ranges (h[5][4] not h[5][8]).

#define PAD 4
#define EPS 1e-5f

constexpr int B = 32, C = 4, H = 512, W = 512;
constexpr int ROWS = 16;               // rows per wave-task
constexpr int NCHUNK = H / ROWS;       // 32
constexpr int NTASK = B * C * NCHUNK;  // 4096 independent waves
constexpr int TPB = 256;
constexpr int WPB = TPB / 64;          // 4 independent waves per block
constexpr int NBLK = NTASK / WPB;      // 1024
constexpr float INV_N = 1.0f / 81.0f;

__device__ __forceinline__ void loadrow(const float* __restrict__ p, int r,
                                        int x0, float4& a, float4& b) {
    const float* q = p + (size_t)r * W + x0;
    a = *(const float4*)q;
    b = *(const float4*)(q + 4);
}

template <int SGN>
__device__ __forceinline__ void fold8(float s[5][8],
                                      const float4& i0, const float4& i1,
                                      const float4& j0, const float4& j1) {
    const float fi[8] = {i0.x, i0.y, i0.z, i0.w, i1.x, i1.y, i1.z, i1.w};
    const float fj[8] = {j0.x, j0.y, j0.z, j0.w, j1.x, j1.y, j1.z, j1.w};
#pragma unroll
    for (int k = 0; k < 8; ++k) {
        const float a = fi[k], b = fj[k];
        if (SGN > 0) {
            s[0][k] += a; s[1][k] += b;
            s[2][k] += a * a; s[3][k] += b * b; s[4][k] += a * b;
        } else {
            s[0][k] -= a; s[1][k] -= b;
            s[2][k] -= a * a; s[3][k] -= b * b; s[4][k] -= a * b;
        }
    }
}

// 9-wide window sums for 4 of this lane's 8 columns.
// HALF=0: own cols 0..3 (needs prev lane's cols 4..7 as left halo)
// HALF=1: own cols 4..7 (needs next lane's cols 0..3 as right halo)
template <int HALF>
__device__ __forceinline__ void hsum4(const float sc[8], int lane, float h[4]) {
    float v[12];
    if (HALF == 0) {
#pragma unroll
        for (int k = 0; k < 4; ++k) {
            const float t = __shfl_up(sc[4 + k], 1, 64);
            v[k] = (lane == 0) ? 0.0f : t;   // image left edge zero-pad
        }
#pragma unroll
        for (int k = 0; k < 8; ++k) v[4 + k] = sc[k];
    } else {
#pragma unroll
        for (int k = 0; k < 8; ++k) v[k] = sc[k];
#pragma unroll
        for (int k = 0; k < 4; ++k) {
            const float t = __shfl_down(sc[k], 1, 64);
            v[8 + k] = (lane == 63) ? 0.0f : t;  // image right edge zero-pad
        }
    }
    // out j uses v[j..j+8]
    float t = v[0] + v[1] + v[2] + v[3] + v[4] + v[5] + v[6] + v[7] + v[8];
    h[0] = t;
    t += v[9]  - v[0]; h[1] = t;
    t += v[10] - v[1]; h[2] = t;
    t += v[11] - v[2]; h[3] = t;
}

__device__ __forceinline__ float cc4(const float h[5][4]) {
    float acc = 0.0f;
#pragma unroll
    for (int k = 0; k < 4; ++k) {
        const float mi = h[0][k] * INV_N;
        const float mj = h[1][k] * INV_N;
        const float vi = h[2][k] * INV_N - mi * mi;
        const float vj = h[3][k] * INV_N - mj * mj;
        const float cv = h[4][k] * INV_N - mi * mj;
        const float den = fmaxf(vi, 0.0f) * fmaxf(vj, 0.0f) + EPS;
        acc += cv * cv * __builtin_amdgcn_rcpf(den);
    }
    return acc;
}

__global__ __launch_bounds__(TPB) void ncc_partial(
        const float* __restrict__ y_pred, const float* __restrict__ y_true,
        float* __restrict__ partial) {
    const int wid = threadIdx.x >> 6;
    const int lane = threadIdx.x & 63;
    // XCD swizzle: consecutive tasks (vertical neighbors sharing halo rows)
    // land on the same XCD's L2. Bijective: NBLK % 8 == 0.
    const int g = (blockIdx.x & 7) * (NBLK / 8) + (blockIdx.x >> 3);
    const int task = g * WPB + wid;                 // bijection over [0,4096)
    const int plane = task >> 5;                    // / NCHUNK
    const int v = task & (NCHUNK - 1);
    const size_t base = (size_t)plane * H * W;
    const float* I = y_true + base;  // reference: I = y_true
    const float* J = y_pred + base;  // reference: J = y_pred
    const int x0 = lane * 8;
    const int y0 = v * ROWS;

    // Running vertical sums over rows [y-4, y+4]: 5 moments x 8 cols.
    float s[5][8];
#pragma unroll
    for (int c = 0; c < 5; ++c)
#pragma unroll
        for (int k = 0; k < 8; ++k) s[c][k] = 0.0f;

    // Prime rows [y0-4, y0+4] ∩ [0,H)   (y0+4 <= 500 < H always)
    for (int r = y0 - PAD; r <= y0 + PAD; ++r) {
        if (r < 0) continue;
        float4 i0, i1, j0, j1;
        loadrow(I, r, x0, i0, i1);
        loadrow(J, r, x0, j0, j1);
        fold8<+1>(s, i0, i1, j0, j1);
    }

    float acc = 0.0f;

    for (int yo = 0; yo < ROWS; ++yo) {
        const int y = y0 + yo;

        // --- issue next-iteration loads; consumed after the cc compute ---
        const int ra = y + PAD + 1;                    // add row y+5
        const bool va = (yo < ROWS - 1) && (ra < H);
        float4 ai0, ai1, aj0, aj1;
        if (va) { loadrow(I, ra, x0, ai0, ai1); loadrow(J, ra, x0, aj0, aj1); }

        const int rs = y - PAD;                        // drop row y-4
        const bool vsub = (yo < ROWS - 1) && (rs >= 0);
        float4 si0, si1, sj0, sj1;
        if (vsub) { loadrow(I, rs, x0, si0, si1); loadrow(J, rs, x0, sj0, sj1); }

        // --- half 0: own cols 0..3 (left halo) ---
        {
            float h[5][4];
            hsum4<0>(s[0], lane, h[0]);
            hsum4<0>(s[1], lane, h[1]);
            hsum4<0>(s[2], lane, h[2]);
            hsum4<0>(s[3], lane, h[3]);
            hsum4<0>(s[4], lane, h[4]);
            acc += cc4(h);
        }
        // --- half 1: own cols 4..7 (right halo) ---
        {
            float h[5][4];
            hsum4<1>(s[0], lane, h[0]);
            hsum4<1>(s[1], lane, h[1]);
            hsum4<1>(s[2], lane, h[2]);
            hsum4<1>(s[3], lane, h[3]);
            hsum4<1>(s[4], lane, h[4]);
            acc += cc4(h);
        }

        // --- fold prefetched rows into the running sums ---
        if (va)   fold8<+1>(s, ai0, ai1, aj0, aj1);
        if (vsub) fold8<-1>(s, si0, si1, sj0, sj1);
    }

    // Per-wave reduction; one partial per task (deterministic slot).
#pragma unroll
    for (int off = 32; off > 0; off >>= 1)
        acc += __shfl_down(acc, off, 64);
    if (lane == 0) partial[task] = acc;
}

__global__ __launch_bounds__(256) void ncc_final(
        const float* __restrict__ partial, float* __restrict__ out) {
    const int t = threadIdx.x;
    float sum = 0.0f;
    for (int i = t; i < NTASK; i += 256) sum += partial[i];
    __shared__ float ws[4];
#pragma unroll
    for (int off = 32; off > 0; off >>= 1)
        sum += __shfl_down(sum, off, 64);
    if ((t & 63) == 0) ws[t >> 6] = sum;
    __syncthreads();
    if (t == 0) {
        const float tot = ws[0] + ws[1] + ws[2] + ws[3];
        out[0] = -tot / (float)((long long)B * C * H * W);
    }
}

extern "C" void kernel_launch(void* const* d_in, const int* in_sizes, int n_in,
                              void* d_out, int out_size, void* d_ws, size_t ws_size,
                              hipStream_t stream) {
    const float* y_pred = (const float*)d_in[0];
    const float* y_true = (const float*)d_in[1];
    float* out = (float*)d_out;
    float* partial = (float*)d_ws;  // NTASK floats = 16 KB

    ncc_partial<<<NBLK, TPB, 0, stream>>>(y_pred, y_true, partial);
    ncc_final<<<1, 256, 0, stream>>>(partial, out);
}